// Round 1
// baseline (142.190 us; speedup 1.0000x reference)
//
#include <hip/hip_runtime.h>
#include <math.h>

#define B_BAGS 512
#define N_REL  128
#define D_DIM  768
#define M_BAG  32
#define DCHUNK 64

// ---------------------------------------------------------------------------
// Kernel A: transpose fc_weight (N x D) -> Wt (D x N) in workspace.
// Tiny (393 KB), runs once per launch before the main kernel (stream-ordered).
// ---------------------------------------------------------------------------
__global__ void transpose_w(const float* __restrict__ W, float* __restrict__ Wt) {
    int flat = blockIdx.x * 256 + threadIdx.x;   // 0 .. 98303
    int n = flat & (N_REL - 1);
    int d = flat >> 7;
    Wt[flat] = W[n * D_DIM + d];                 // coalesced write, strided read
}

// ---------------------------------------------------------------------------
// Kernel B: one block per bag.
//   Phase 1: G[m][n] = bag[m] . w[n]   (32x128 per bag), LDS-tiled fp32 GEMM
//   Phase 2: per-n masked softmax over m -> sm; online softmax over k of
//            full[n][k] = sum_m sm[m]*G[m][k] + bias[k]; output diag prob.
// ---------------------------------------------------------------------------
__global__ __launch_bounds__(256, 2) void bag_attn(
    const float* __restrict__ rep,    // nsum x 768
    const float* __restrict__ bias,   // 128
    const int*   __restrict__ scope,  // B x 2
    const float* __restrict__ Wt,     // 768 x 128 (transposed weight)
    float*       __restrict__ out,    // B x 128
    int nsum)
{
    __shared__ float As[M_BAG][DCHUNK + 4];    // 32 x 68  (+4 pad: bank rotate)
    __shared__ float Bs[DCHUNK][N_REL + 4];    // 64 x 132
    __shared__ float Gs[M_BAG][N_REL + 4];     // 32 x 132
    __shared__ float redM[256], redL[256], redD[256];

    const int t = threadIdx.x;
    const int b = blockIdx.x;
    const int start = scope[2 * b];
    const int size  = scope[2 * b + 1] - start;   // in [8, 25)

    const int ni = t & 31;    // n-group: n = ni*4 .. ni*4+3
    const int mi = t >> 5;    // m-group: m = mi*4 .. mi*4+3

    float acc[4][4];
    #pragma unroll
    for (int r = 0; r < 4; ++r)
        #pragma unroll
        for (int c = 0; c < 4; ++c) acc[r][c] = 0.f;

    // ---------------- Phase 1: G = bag @ Wt ----------------
    for (int c0 = 0; c0 < D_DIM; c0 += DCHUNK) {
        // stage A: 32 rows x 64 cols (512 float4, 2 per thread)
        #pragma unroll
        for (int i = 0; i < 2; ++i) {
            int flat = i * 256 + t;
            int m = flat >> 4;          // 0..31
            int g = flat & 15;          // 0..15
            int row = start + m;
            row = (row > nsum - 1) ? (nsum - 1) : row;   // clip like reference
            const float4 v = *(const float4*)&rep[(size_t)row * D_DIM + c0 + g * 4];
            *(float4*)&As[m][g * 4] = v;
        }
        // stage B: 64 x 128 (2048 float4, 8 per thread) — simple copy from Wt
        #pragma unroll
        for (int i = 0; i < 8; ++i) {
            int flat = i * 256 + t;
            int dd = flat >> 5;         // 0..63
            int nq = flat & 31;         // 0..31
            const float4 v = *(const float4*)&Wt[(size_t)(c0 + dd) * N_REL + nq * 4];
            *(float4*)&Bs[dd][nq * 4] = v;
        }
        __syncthreads();

        #pragma unroll 4
        for (int dd = 0; dd < DCHUNK; dd += 4) {
            float4 a[4], bb[4];
            #pragma unroll
            for (int r = 0; r < 4; ++r) a[r]  = *(const float4*)&As[mi * 4 + r][dd];
            #pragma unroll
            for (int j = 0; j < 4; ++j) bb[j] = *(const float4*)&Bs[dd + j][ni * 4];
            #pragma unroll
            for (int r = 0; r < 4; ++r) {
                const float* ap = (const float*)&a[r];
                #pragma unroll
                for (int j = 0; j < 4; ++j) {
                    const float av = ap[j];
                    const float* bp = (const float*)&bb[j];
                    acc[r][0] += av * bp[0];
                    acc[r][1] += av * bp[1];
                    acc[r][2] += av * bp[2];
                    acc[r][3] += av * bp[3];
                }
            }
        }
        __syncthreads();
    }

    // write G tile
    #pragma unroll
    for (int r = 0; r < 4; ++r) {
        float4 v = make_float4(acc[r][0], acc[r][1], acc[r][2], acc[r][3]);
        *(float4*)&Gs[mi * 4 + r][ni * 4] = v;
    }
    __syncthreads();

    // ---------------- Phase 2 ----------------
    const int n = t & 127;      // relation this thread owns
    const int h = t >> 7;       // which k-half this thread covers

    // masked softmax over m of column G[:, n]  (size is block-uniform)
    float sm[M_BAG];
    float gmax = -INFINITY;
    #pragma unroll
    for (int m = 0; m < M_BAG; ++m) {
        float g = Gs[m][n];
        sm[m] = g;
        if (m < size) gmax = fmaxf(gmax, g);
    }
    float ssum = 0.f;
    #pragma unroll
    for (int m = 0; m < M_BAG; ++m) {
        float e = __expf(sm[m] - gmax);
        e = (m < size) ? e : 0.f;
        sm[m] = e;
        ssum += e;
    }
    const float inv = 1.f / ssum;
    #pragma unroll
    for (int m = 0; m < M_BAG; ++m) sm[m] *= inv;

    // online softmax over k of full[n][k] = bias[k] + sum_m sm[m]*G[m][k]
    float mx = -INFINITY, l = 0.f, sd = 0.f;
    const int kbase = h * 64;
    #pragma unroll 4
    for (int kk = 0; kk < 64; kk += 4) {
        const int k = kbase + kk;
        float4 b4 = *(const float4*)&bias[k];    // wave-uniform -> scalar load
        float s0 = b4.x, s1 = b4.y, s2 = b4.z, s3 = b4.w;
        #pragma unroll
        for (int m = 0; m < M_BAG; ++m) {
            const float4 g = *(const float4*)&Gs[m][k];  // broadcast read
            const float w = sm[m];
            s0 += w * g.x; s1 += w * g.y; s2 += w * g.z; s3 += w * g.w;
        }
        float s[4] = {s0, s1, s2, s3};
        #pragma unroll
        for (int j = 0; j < 4; ++j) {
            const float sj = s[j];
            const float mnew = fmaxf(mx, sj);
            l = l * __expf(mx - mnew) + __expf(sj - mnew);
            mx = mnew;
            sd = (k + j == n) ? sj : sd;
        }
    }

    // merge the two k-halves via LDS
    redM[t] = mx; redL[t] = l; redD[t] = sd;
    __syncthreads();
    if (t < 128) {
        const float m0 = redM[t],       l0 = redL[t],       d0 = redD[t];
        const float m1 = redM[t + 128], l1 = redL[t + 128], d1 = redD[t + 128];
        const float M  = fmaxf(m0, m1);
        const float L  = l0 * __expf(m0 - M) + l1 * __expf(m1 - M);
        const float sdiag = (t < 64) ? d0 : d1;   // k==n lives in half n/64
        out[b * N_REL + t] = __expf(sdiag - M) / L;
    }
}

// ---------------------------------------------------------------------------
extern "C" void kernel_launch(void* const* d_in, const int* in_sizes, int n_in,
                              void* d_out, int out_size, void* d_ws, size_t ws_size,
                              hipStream_t stream) {
    const float* rep   = (const float*)d_in[0];
    const float* W     = (const float*)d_in[1];
    const float* bias  = (const float*)d_in[2];
    const int*   scope = (const int*)d_in[3];
    // d_in[4] = max_bag (always 32 for this problem) — hardcoded as M_BAG.

    const int nsum = in_sizes[0] / D_DIM;
    float* Wt = (float*)d_ws;   // 768*128 floats = 393216 B of workspace

    transpose_w<<<(D_DIM * N_REL) / 256, 256, 0, stream>>>(W, Wt);
    bag_attn<<<B_BAGS, 256, 0, stream>>>(rep, bias, scope, Wt, (float*)d_out, nsum);
}

// Round 2
// 113.675 us; speedup vs baseline: 1.2508x; 1.2508x over previous
//
#include <hip/hip_runtime.h>
#include <math.h>

#define B_BAGS 512
#define N_REL  128
#define D_DIM  768
#define M_BAG  32
#define KSTEPS 24      // 768/32 global K-steps (K=32 per MFMA)
#define CSTEPS 12      // K-steps per chunk (chunk = 384 of K)

typedef __attribute__((ext_vector_type(8))) short  bf16x8;
typedef __attribute__((ext_vector_type(4))) float  f32x4;

// pack truncated-bf16 of (f0,f1) -> one uint (low short = bf16(f0))
__device__ inline unsigned pack_hi(float f0, float f1) {
    return __builtin_amdgcn_perm(__float_as_uint(f1), __float_as_uint(f0), 0x07060302u);
}
__device__ inline float trunc_res(float f) {   // f - bf16_trunc(f)
    return f - __uint_as_float(__float_as_uint(f) & 0xFFFF0000u);
}

// ---------------------------------------------------------------------------
// Prep: build fragment-ordered bf16 hi/lo of W for the MFMA B-operand.
// Layout (shorts): Bfrag[s][tile][p][lane][8],  s<24, tile<8, p in {hi,lo}.
// Element = W[n][k],  n = tile*16 + (lane&15),  k = s*32 + (lane>>4)*8 + j.
// ---------------------------------------------------------------------------
__global__ void build_bfrag(const float* __restrict__ W, unsigned* __restrict__ Bfrag) {
    int flat = blockIdx.x * 256 + threadIdx.x;     // 0..12287
    int lane = flat & 63;
    int tile = (flat >> 6) & 7;
    int s    = flat >> 9;                          // 0..23
    int n  = tile * 16 + (lane & 15);
    int k0 = s * 32 + (lane >> 4) * 8;
    const float* src = &W[n * D_DIM + k0];
    float f[8];
    #pragma unroll
    for (int j = 0; j < 8; ++j) f[j] = src[j];
    unsigned hi[4], lo[4];
    #pragma unroll
    for (int q = 0; q < 4; ++q) {
        hi[q] = pack_hi(f[2*q], f[2*q+1]);
        lo[q] = pack_hi(trunc_res(f[2*q]), trunc_res(f[2*q+1]));
    }
    unsigned base = (unsigned)(((s * 8 + tile) * 2) * 64 + lane) * 4;   // uints
    *(uint4*)&Bfrag[base]          = make_uint4(hi[0], hi[1], hi[2], hi[3]);
    *(uint4*)&Bfrag[base + 64 * 4] = make_uint4(lo[0], lo[1], lo[2], lo[3]);
}

// ---------------------------------------------------------------------------
// Main: one block per bag.
// Phase 1 (MFMA): G[m][n] = bag[m].w[n] via bf16x3 (hi*hi + hi*lo + lo*hi).
// Phase 2 (VALU, unchanged from r1): masked softmax over m, then online
// softmax over k of full = sm@G + bias, output diagonal prob.
// ---------------------------------------------------------------------------
__global__ __launch_bounds__(256, 2) void bag_attn(
    const float*  __restrict__ rep,    // nsum x 768
    const float*  __restrict__ bias,   // 128
    const int*    __restrict__ scope,  // B x 2
    const unsigned short* __restrict__ Bfrag,  // fragment-ordered W hi/lo
    float*        __restrict__ out,    // B x 128
    int nsum)
{
    // A-fragment LDS, region-skewed (65 slots of 16B per [s][h] region).
    __shared__ unsigned AhS[CSTEPS * 2 * 65 * 4];   // 24960 B
    __shared__ unsigned AlS[CSTEPS * 2 * 65 * 4];   // 24960 B
    __shared__ float Gs[M_BAG][N_REL + 4];          // 16896 B
    __shared__ float redM[256], redL[256], redD[256];

    const int t = threadIdx.x;
    const int b = blockIdx.x;
    const int start = scope[2 * b];
    const int size  = scope[2 * b + 1] - start;

    const int wv   = t >> 6;
    const int lane = t & 63;

    f32x4 acc[2][2][3];
    #pragma unroll
    for (int h = 0; h < 2; ++h)
        #pragma unroll
        for (int tt = 0; tt < 2; ++tt)
            #pragma unroll
            for (int q = 0; q < 3; ++q)
                acc[h][tt][q] = f32x4{0.f, 0.f, 0.f, 0.f};

    const int m_st = t >> 3;          // staging row 0..31
    const int r_st = t & 7;
    int row = start + m_st;
    row = (row > nsum - 1) ? (nsum - 1) : row;
    const float* rp0 = &rep[(size_t)row * D_DIM];

    for (int c = 0; c < 2; ++c) {
        // ---- stage A chunk (32 x 384) as bf16 hi/lo fragments ----
        const float* rp = rp0 + c * 384;
        #pragma unroll
        for (int i = 0; i < 6; ++i) {
            const int kk8 = r_st + 8 * i;          // 0..47 (8-elem k group)
            const float4 v0 = *(const float4*)&rp[kk8 * 8];
            const float4 v1 = *(const float4*)&rp[kk8 * 8 + 4];
            const int s  = kk8 >> 2;
            const int kg = kk8 & 3;
            const int dst = ((s * 2 + (m_st >> 4)) * 65 + kg * 16 + (m_st & 15)) * 4;
            *(uint4*)&AhS[dst] = make_uint4(
                pack_hi(v0.x, v0.y), pack_hi(v0.z, v0.w),
                pack_hi(v1.x, v1.y), pack_hi(v1.z, v1.w));
            *(uint4*)&AlS[dst] = make_uint4(
                pack_hi(trunc_res(v0.x), trunc_res(v0.y)),
                pack_hi(trunc_res(v0.z), trunc_res(v0.w)),
                pack_hi(trunc_res(v1.x), trunc_res(v1.y)),
                pack_hi(trunc_res(v1.z), trunc_res(v1.w)));
        }
        __syncthreads();

        // ---- MFMA over this chunk ----
        #pragma unroll 4
        for (int s = 0; s < CSTEPS; ++s) {
            const int gs = c * CSTEPS + s;
            const bf16x8 ah0 = *(const bf16x8*)&AhS[((s * 2 + 0) * 65 + lane) * 4];
            const bf16x8 ah1 = *(const bf16x8*)&AhS[((s * 2 + 1) * 65 + lane) * 4];
            const bf16x8 al0 = *(const bf16x8*)&AlS[((s * 2 + 0) * 65 + lane) * 4];
            const bf16x8 al1 = *(const bf16x8*)&AlS[((s * 2 + 1) * 65 + lane) * 4];
            #pragma unroll
            for (int tt = 0; tt < 2; ++tt) {
                const int tid8 = gs * 8 + (wv * 2 + tt);
                const bf16x8 bh = *(const bf16x8*)&Bfrag[(unsigned)((tid8 * 2 + 0) * 64 + lane) * 8];
                const bf16x8 bl = *(const bf16x8*)&Bfrag[(unsigned)((tid8 * 2 + 1) * 64 + lane) * 8];
                acc[0][tt][0] = __builtin_amdgcn_mfma_f32_16x16x32_bf16(ah0, bh, acc[0][tt][0], 0, 0, 0);
                acc[1][tt][0] = __builtin_amdgcn_mfma_f32_16x16x32_bf16(ah1, bh, acc[1][tt][0], 0, 0, 0);
                acc[0][tt][1] = __builtin_amdgcn_mfma_f32_16x16x32_bf16(ah0, bl, acc[0][tt][1], 0, 0, 0);
                acc[1][tt][1] = __builtin_amdgcn_mfma_f32_16x16x32_bf16(ah1, bl, acc[1][tt][1], 0, 0, 0);
                acc[0][tt][2] = __builtin_amdgcn_mfma_f32_16x16x32_bf16(al0, bh, acc[0][tt][2], 0, 0, 0);
                acc[1][tt][2] = __builtin_amdgcn_mfma_f32_16x16x32_bf16(al1, bh, acc[1][tt][2], 0, 0, 0);
            }
        }
        __syncthreads();   // protect A LDS before restaging / Gs write
    }

    // ---- write G tiles: C/D layout col=lane&15, row=(lane>>4)*4+reg ----
    #pragma unroll
    for (int h = 0; h < 2; ++h)
        #pragma unroll
        for (int tt = 0; tt < 2; ++tt) {
            const f32x4 cw = acc[h][tt][0] + acc[h][tt][1] + acc[h][tt][2];
            const int n    = wv * 32 + tt * 16 + (lane & 15);
            const int mrow = h * 16 + (lane >> 4) * 4;
            #pragma unroll
            for (int rg = 0; rg < 4; ++rg) Gs[mrow + rg][n] = cw[rg];
        }
    __syncthreads();

    // ---------------- Phase 2 (unchanged from round 1) ----------------
    const int n = t & 127;
    const int h = t >> 7;

    float sm[M_BAG];
    float gmax = -INFINITY;
    #pragma unroll
    for (int m = 0; m < M_BAG; ++m) {
        float g = Gs[m][n];
        sm[m] = g;
        if (m < size) gmax = fmaxf(gmax, g);
    }
    float ssum = 0.f;
    #pragma unroll
    for (int m = 0; m < M_BAG; ++m) {
        float e = __expf(sm[m] - gmax);
        e = (m < size) ? e : 0.f;
        sm[m] = e;
        ssum += e;
    }
    const float inv = 1.f / ssum;
    #pragma unroll
    for (int m = 0; m < M_BAG; ++m) sm[m] *= inv;

    float mx = -INFINITY, l = 0.f, sd = 0.f;
    const int kbase = h * 64;
    #pragma unroll 4
    for (int kk = 0; kk < 64; kk += 4) {
        const int k = kbase + kk;
        float4 b4 = *(const float4*)&bias[k];
        float s0 = b4.x, s1 = b4.y, s2 = b4.z, s3 = b4.w;
        #pragma unroll
        for (int m = 0; m < M_BAG; ++m) {
            const float4 g = *(const float4*)&Gs[m][k];   // same-addr broadcast
            const float w = sm[m];
            s0 += w * g.x; s1 += w * g.y; s2 += w * g.z; s3 += w * g.w;
        }
        float s[4] = {s0, s1, s2, s3};
        #pragma unroll
        for (int j = 0; j < 4; ++j) {
            const float sj = s[j];
            const float mnew = fmaxf(mx, sj);
            l = l * __expf(mx - mnew) + __expf(sj - mnew);
            mx = mnew;
            sd = (k + j == n) ? sj : sd;
        }
    }

    redM[t] = mx; redL[t] = l; redD[t] = sd;
    __syncthreads();
    if (t < 128) {
        const float m0 = redM[t],       l0 = redL[t],       d0 = redD[t];
        const float m1 = redM[t + 128], l1 = redL[t + 128], d1 = redD[t + 128];
        const float M  = fmaxf(m0, m1);
        const float L  = l0 * __expf(m0 - M) + l1 * __expf(m1 - M);
        const float sdiag = (t < 64) ? d0 : d1;
        out[b * N_REL + t] = __expf(sdiag - M) / L;
    }
}

// ---------------------------------------------------------------------------
extern "C" void kernel_launch(void* const* d_in, const int* in_sizes, int n_in,
                              void* d_out, int out_size, void* d_ws, size_t ws_size,
                              hipStream_t stream) {
    const float* rep   = (const float*)d_in[0];
    const float* W     = (const float*)d_in[1];
    const float* bias  = (const float*)d_in[2];
    const int*   scope = (const int*)d_in[3];

    const int nsum = in_sizes[0] / D_DIM;
    unsigned* Bfrag = (unsigned*)d_ws;   // 393216 B

    build_bfrag<<<48, 256, 0, stream>>>(W, Bfrag);
    bag_attn<<<B_BAGS, 256, 0, stream>>>(rep, bias, scope,
                                         (const unsigned short*)Bfrag,
                                         (float*)d_out, nsum);
}